// Round 11
// baseline (370.805 us; speedup 1.0000x reference)
//
#include <hip/hip_runtime.h>
#include <math.h>

constexpr int D_DIM  = 2048;   // feature dim (FFT length)
constexpr int HALF_D = 1024;
constexpr int B_DIM  = 2;
constexpr int S_DIM  = 4096;
constexpr int NROW   = B_DIM * S_DIM;      // 8192
constexpr int NCHUNK = 64;                 // scan chunks along S
constexpr int CHLEN  = S_DIM / NCHUNK;     // 64
constexpr float EPS_ = 1e-8f;

typedef __attribute__((ext_vector_type(8))) short  short8;   // bf16x8 frag
typedef __attribute__((ext_vector_type(8))) unsigned short ushort8;
typedef __attribute__((ext_vector_type(4))) float  f32x4;    // MFMA acc

__device__ __forceinline__ float2 mkf2(float x, float y){ float2 r; r.x=x; r.y=y; return r; }
__device__ __forceinline__ float2 cmulf(float2 a, float2 b){
  return mkf2(fmaf(a.x, b.x, -a.y*b.y), fmaf(a.x, b.y, a.y*b.x));
}
__device__ __forceinline__ unsigned short f2bf(float x){
  unsigned u = __float_as_uint(x);
  u += 0x7fff + ((u >> 16) & 1);           // round-to-nearest-even
  return (unsigned short)(u >> 16);
}
__device__ __forceinline__ float bf2f(unsigned short h){
  return __uint_as_float(((unsigned)h) << 16);
}
__device__ __forceinline__ unsigned packbf2(float a, float b){
  return (unsigned)f2bf(a) | ((unsigned)f2bf(b) << 16);
}

// ------------------------------------------------------------ fp32→bf16 ---
__global__ __launch_bounds__(256)
void cvt_hs(const float* __restrict__ hs, unsigned short* __restrict__ hsb)
{
  int i = blockIdx.x * 256 + threadIdx.x;          // n8 = 2097152 total
  const float4* p = (const float4*)hs + (size_t)i * 2;
  float4 a = p[0], b = p[1];
  ushort8 o;
  o[0]=f2bf(a.x); o[1]=f2bf(a.y); o[2]=f2bf(a.z); o[3]=f2bf(a.w);
  o[4]=f2bf(b.x); o[5]=f2bf(b.y); o[6]=f2bf(b.z); o[7]=f2bf(b.w);
  *(ushort8*)(hsb + (size_t)i * 8) = o;
}

// ------------------------------------------------------------- FFT core ---
// 2048-pt FFT, 256 threads, radix 8-8-8-4 macro-stages, register butterflies.
__device__ __forceinline__ int XS(int i){ return i ^ (((i >> 5) ^ (i >> 10)) & 31); }
__device__ __forceinline__ int TS(int i){ return i ^ ((i >> 5) & 31); }

__device__ __forceinline__ float2 mulmi(float2 w){ return mkf2(w.y, -w.x); }   // w * (-i)
__device__ __forceinline__ float2 mulw8(float2 w){                              // w * e^{-i pi/4}
  const float c = 0.70710678118654752f;
  return mkf2(c * (w.x + w.y), c * (w.y - w.x));
}
__device__ __forceinline__ void bfly(float2& a, float2& b, float2 w){
  float2 v = cmulf(w, b);
  b = mkf2(a.x - v.x, a.y - v.y);
  a = mkf2(a.x + v.x, a.y + v.y);
}
__device__ __forceinline__ void bflyc(float2& a, float2& b, float2 w){
  float2 d = mkf2(a.x - b.x, a.y - b.y);
  a = mkf2(a.x + b.x, a.y + b.y);
  b = mkf2(fmaf(d.x, w.x, d.y * w.y), fmaf(d.y, w.x, -d.x * w.y));  // d * conj(w)
}

__device__ __forceinline__ void fwd8(float2 e[8], float2 wA, float2 wB0, float2 wC0){
  bfly(e[0], e[1], wA); bfly(e[2], e[3], wA); bfly(e[4], e[5], wA); bfly(e[6], e[7], wA);
  float2 wB1 = mulmi(wB0);
  bfly(e[0], e[2], wB0); bfly(e[1], e[3], wB1); bfly(e[4], e[6], wB0); bfly(e[5], e[7], wB1);
  float2 wC1 = mulw8(wC0), wC2 = mulmi(wC0), wC3 = mulmi(wC1);
  bfly(e[0], e[4], wC0); bfly(e[1], e[5], wC1); bfly(e[2], e[6], wC2); bfly(e[3], e[7], wC3);
}
__device__ __forceinline__ void inv8(float2 e[8], float2 wA, float2 wB0, float2 wC0){
  float2 wC1 = mulw8(wC0), wC2 = mulmi(wC0), wC3 = mulmi(wC1);
  bflyc(e[0], e[4], wC0); bflyc(e[1], e[5], wC1); bflyc(e[2], e[6], wC2); bflyc(e[3], e[7], wC3);
  float2 wB1 = mulmi(wB0);
  bflyc(e[0], e[2], wB0); bflyc(e[1], e[3], wB1); bflyc(e[4], e[6], wB0); bflyc(e[5], e[7], wB1);
  bflyc(e[0], e[1], wA); bflyc(e[2], e[3], wA); bflyc(e[4], e[5], wA); bflyc(e[6], e[7], wA);
}

__device__ __forceinline__ float2 twld(const float* twr, const float* twi, int i){
  int s = TS(i);
  return mkf2(twr[s], twi[s]);
}

__device__ __forceinline__ void load_twiddles_ls(float* twr, float* twi, int t)
{
  for (int i = t; i < HALF_D; i += 256) {
    float sv, cv;
    sincosf(-6.283185307179586f * (float)i / (float)D_DIM, &sv, &cv);
    int s = TS(i); twr[s] = cv; twi[s] = sv;
  }
}

__device__ void fft_fwd(float2* X, const float* twr, const float* twi, int t)
{
  const float2 one = mkf2(1.f, 0.f);
  {                                   // MS1
    int b = 8 * t;
    float2 e[8];
#pragma unroll
    for (int r = 0; r < 8; ++r) e[r] = X[XS(b + r)];
    fwd8(e, one, one, one);
#pragma unroll
    for (int r = 0; r < 8; ++r) X[XS(b + r)] = e[r];
  }
  __syncthreads();
  {                                   // MS2
    int u = t >> 5, b = 64 * (t & 31) + u;
    float2 e[8];
#pragma unroll
    for (int r = 0; r < 8; ++r) e[r] = X[XS(b + 8 * r)];
    fwd8(e, twld(twr,twi,128*u), twld(twr,twi,64*u), twld(twr,twi,32*u));
#pragma unroll
    for (int r = 0; r < 8; ++r) X[XS(b + 8 * r)] = e[r];
  }
  __syncthreads();
  {                                   // MS3
    int u = t & 63, b = 512 * (t >> 6) + u;
    float2 e[8];
#pragma unroll
    for (int r = 0; r < 8; ++r) e[r] = X[XS(b + 64 * r)];
    fwd8(e, twld(twr,twi,16*u), twld(twr,twi,8*u), twld(twr,twi,4*u));
#pragma unroll
    for (int r = 0; r < 8; ++r) X[XS(b + 64 * r)] = e[r];
  }
  __syncthreads();
#pragma unroll
  for (int h = 0; h < 2; ++h) {       // MS4: radix-4
    int u = t + 256 * h;
    float2 f[4];
#pragma unroll
    for (int r = 0; r < 4; ++r) f[r] = X[XS(u + 512 * r)];
    float2 wA = twld(twr,twi,2*u), wB0 = twld(twr,twi,u), wB1 = mulmi(wB0);
    bfly(f[0], f[1], wA);  bfly(f[2], f[3], wA);
    bfly(f[0], f[2], wB0); bfly(f[1], f[3], wB1);
#pragma unroll
    for (int r = 0; r < 4; ++r) X[XS(u + 512 * r)] = f[r];
  }
  __syncthreads();
}

__device__ void fft_inv(float2* X, const float* twr, const float* twi, int t)
{
  const float2 one = mkf2(1.f, 0.f);
#pragma unroll
  for (int h = 0; h < 2; ++h) {       // MS4'
    int u = t + 256 * h;
    float2 f[4];
#pragma unroll
    for (int r = 0; r < 4; ++r) f[r] = X[XS(u + 512 * r)];
    float2 wA = twld(twr,twi,2*u), wB0 = twld(twr,twi,u), wB1 = mulmi(wB0);
    bflyc(f[0], f[2], wB0); bflyc(f[1], f[3], wB1);
    bflyc(f[0], f[1], wA);  bflyc(f[2], f[3], wA);
#pragma unroll
    for (int r = 0; r < 4; ++r) X[XS(u + 512 * r)] = f[r];
  }
  __syncthreads();
  {                                   // MS3'
    int u = t & 63, b = 512 * (t >> 6) + u;
    float2 e[8];
#pragma unroll
    for (int r = 0; r < 8; ++r) e[r] = X[XS(b + 64 * r)];
    inv8(e, twld(twr,twi,16*u), twld(twr,twi,8*u), twld(twr,twi,4*u));
#pragma unroll
    for (int r = 0; r < 8; ++r) X[XS(b + 64 * r)] = e[r];
  }
  __syncthreads();
  {                                   // MS2'
    int u = t >> 5, b = 64 * (t & 31) + u;
    float2 e[8];
#pragma unroll
    for (int r = 0; r < 8; ++r) e[r] = X[XS(b + 8 * r)];
    inv8(e, twld(twr,twi,128*u), twld(twr,twi,64*u), twld(twr,twi,32*u));
#pragma unroll
    for (int r = 0; r < 8; ++r) X[XS(b + 8 * r)] = e[r];
  }
  __syncthreads();
  {                                   // MS1'
    int b = 8 * t;
    float2 e[8];
#pragma unroll
    for (int r = 0; r < 8; ++r) e[r] = X[XS(b + r)];
    inv8(e, one, one, one);
#pragma unroll
    for (int r = 0; r < 8; ++r) X[XS(b + r)] = e[r];
  }
  __syncthreads();
}

// ----------------------------------------------- weight-column FFT --------
// wspec[w][r][d] bf16: r = packed half-spectrum row of FFT over e of W[e][d]:
// r0=Re[0], r1=Re[1024], r2f/2f+1=Re/Im[f].  Block handles 2 columns (one
// packed complex FFT).  d-range XCD-partitioned so the 8 blocks sharing a
// 64B src line sit on one XCD (fetch stays ~50MB).
__global__ __launch_bounds__(256)
void wfft_kernel(const float* __restrict__ Wq, const float* __restrict__ Wk,
                 const float* __restrict__ Wv, unsigned short* __restrict__ wspec)
{
  __shared__ float2 X[D_DIM];
  __shared__ float twr[HALF_D], twi[HALF_D];
  const int t = threadIdx.x;
  const int b = blockIdx.x;                        // 0..3071
  const int w = b >> 10, j = b & 1023;
  const int d0 = (j & 7) * 256 + (j >> 3) * 2;     // XCD owns a 256-col slice
  const float* Ws = (w == 0) ? Wq : (w == 1) ? Wk : Wv;

  load_twiddles_ls(twr, twi, t);
  for (int e = t; e < D_DIM; e += 256) {
    int p = __brev((unsigned)e) >> 21;
    float2 v = *(const float2*)(Ws + (size_t)e * 2048 + d0);
    X[XS(p)] = v;
  }
  __syncthreads();
  fft_fwd(X, twr, twi, t);

  unsigned short* w0 = wspec + ((size_t)w * 2048) * 2048 + d0;
  for (int d = t; d < HALF_D; d += 256) {
    if (d == 0) {
      float2 z0 = X[XS(0)], zn = X[XS(HALF_D)];
      *(unsigned*)(w0)        = packbf2(z0.x, z0.y);        // Re[0]   (c0,c1)
      *(unsigned*)(w0 + 2048) = packbf2(zn.x, zn.y);        // Re[1024]
    } else {
      float2 A = X[XS(d)], Bc = X[XS(D_DIM - d)];
      float2 Bj = mkf2(Bc.x, -Bc.y);
      float2 F0 = mkf2(0.5f * (A.x + Bj.x), 0.5f * (A.y + Bj.y));
      float2 tt = mkf2(0.5f * (A.x - Bj.x), 0.5f * (A.y - Bj.y));
      float2 F1 = mkf2(tt.y, -tt.x);
      *(unsigned*)(w0 + (size_t)(2 * d) * 2048)     = packbf2(F0.x, F1.x);
      *(unsigned*)(w0 + (size_t)(2 * d + 1) * 2048) = packbf2(F0.y, F1.y);
    }
  }
}

// bias FFT: biasF[w][r] f32, same packed-row convention (real input: Z = F(b))
__global__ __launch_bounds__(256)
void biasfft_kernel(const float* __restrict__ bq, const float* __restrict__ bk,
                    const float* __restrict__ bv, float* __restrict__ biasF)
{
  __shared__ float2 X[D_DIM];
  __shared__ float twr[HALF_D], twi[HALF_D];
  const int t = threadIdx.x;
  const int w = blockIdx.x;
  const float* bs = (w == 0) ? bq : (w == 1) ? bk : bv;
  load_twiddles_ls(twr, twi, t);
  for (int e = t; e < D_DIM; e += 256) {
    int p = __brev((unsigned)e) >> 21;
    X[XS(p)] = mkf2(bs[e], 0.f);
  }
  __syncthreads();
  fft_fwd(X, twr, twi, t);
  float* o = biasF + (size_t)w * 2048;
  for (int d = t; d < HALF_D; d += 256) {
    if (d == 0) { o[0] = X[XS(0)].x; o[1] = X[XS(HALF_D)].x; }
    else { float2 z = X[XS(d)]; o[2*d] = z.x; o[2*d+1] = z.y; }
  }
}

// -------------- fused q/k/v 256x256 MFMA GEMM, 8-phase schedule (m201) ----
// A [8192][2048] bf16, Wc = wspec [6144][2048] bf16 (spectral weights).
// Output columns ARE packed spectra; q -> qb, k/v -> kvb rows.  Unchanged
// R8 schedule: BK=64, 8 phases/2 K-tiles, vmcnt(4) @ ph3/7, XOR swizzle.
__global__ __launch_bounds__(512, 2)
void gemm_fused(const unsigned short* __restrict__ A,
                const unsigned short* __restrict__ Wc,
                const float* __restrict__ biasF,
                unsigned short* __restrict__ qb, unsigned short* __restrict__ kvb)
{
  constexpr int K = 2048, NITER = 16;             // 32 K-tiles, 2/iter
  __shared__ unsigned short lds[65536];           // 128 KB: A[2][16K] B[2][16K]
  const int tid  = threadIdx.x;
  const int wid  = tid >> 6, lane = tid & 63;
  const int wr   = wid >> 2, wc = wid & 3;

  int bid = blockIdx.x;
  int sw  = (bid & 7) * 96 + (bid >> 3);
  const int bm = (sw / 24) * 256, bn = (sw % 24) * 256;

  const int srow = tid >> 3;                       // 0..63
  const int skc  = ((tid & 7) ^ (srow & 7)) * 8;
  const unsigned short* Ag = A  + (size_t)(bm + srow) * K + skc;
  const unsigned short* Bg = Wc + (size_t)(bn + srow) * K + skc;
  unsigned short* Al = lds;
  unsigned short* Bl = lds + 32768;
  const int stoff = wid * 512;

  auto stA = [&](int kt, int d, int h, int r) {
    __builtin_amdgcn_global_load_lds(
      (const __attribute__((address_space(1))) void*)(Ag + (size_t)(h * 128 + r * 64) * K + kt * 64),
      (__attribute__((address_space(3))) void*)(Al + d * 16384 + h * 8192 + r * 4096 + stoff),
      16, 0, 0);
  };
  auto stB = [&](int kt, int d, int h, int r) {
    __builtin_amdgcn_global_load_lds(
      (const __attribute__((address_space(1))) void*)(Bg + (size_t)(h * 128 + r * 64) * K + kt * 64),
      (__attribute__((address_space(3))) void*)(Bl + d * 16384 + h * 8192 + r * 4096 + stoff),
      16, 0, 0);
  };

  const int frow = lane & 15;
  const int kq   = lane >> 4;
  int ksw[2];
  ksw[0] = ((0 * 4 + kq) ^ (frow & 7)) * 8;
  ksw[1] = ((1 * 4 + kq) ^ (frow & 7)) * 8;
  const int arow0 = (wr * 128 + frow) * 64;
  const int brow0 = (wc * 64 + frow) * 64;

  f32x4 acc[8][4];
#pragma unroll
  for (int i = 0; i < 8; ++i)
#pragma unroll
    for (int j = 0; j < 4; ++j) acc[i][j] = (f32x4){0.f, 0.f, 0.f, 0.f};

  stA(0, 0, 0, 0); stA(0, 0, 0, 1); stA(0, 0, 1, 0); stA(0, 0, 1, 1);
  stB(0, 0, 0, 0); stB(0, 0, 0, 1); stB(0, 0, 1, 0); stB(0, 0, 1, 1);
  stB(1, 1, 0, 0); stB(1, 1, 0, 1); stB(1, 1, 1, 0); stB(1, 1, 1, 1);
  asm volatile("s_waitcnt vmcnt(4)" ::: "memory");
  __builtin_amdgcn_s_barrier();
  __builtin_amdgcn_sched_barrier(0);

#pragma unroll 1
  for (int it = 0; it < NITER; ++it) {
    const bool nl = (it < NITER - 1);
    const int t1 = 2 * it + 1;
    short8 bfr[8];
#pragma unroll
    for (int ph = 0; ph < 8; ++ph) {
      const int g  = ph & 3;
      const int db = ph >> 2;
      const unsigned short* Ab = Al + db * 16384;
      const unsigned short* Bb = Bl + db * 16384;

      if      (ph == 0) { stA(t1, 1, 0, 0); stA(t1, 1, 0, 1); }
      else if (ph == 1) { stA(t1, 1, 1, 0); stA(t1, 1, 1, 1); }
      else if (ph == 2) { if (nl) { stB(t1 + 1, 0, 0, 0); stB(t1 + 1, 0, 0, 1); } }
      else if (ph == 3) { if (nl) { stB(t1 + 1, 0, 1, 0); stB(t1 + 1, 0, 1, 1); } }
      else if (ph == 4) { if (nl) { stA(t1 + 1, 0, 0, 0); stA(t1 + 1, 0, 0, 1); } }
      else if (ph == 5) { if (nl) { stA(t1 + 1, 0, 1, 0); stA(t1 + 1, 0, 1, 1); } }
      else if (ph == 6) { if (nl) { stB(t1 + 2, 1, 0, 0); stB(t1 + 2, 1, 0, 1); } }
      else              { if (nl) { stB(t1 + 2, 1, 1, 0); stB(t1 + 2, 1, 1, 1); } }

      short8 af[2][2];
#pragma unroll
      for (int q = 0; q < 2; ++q)
#pragma unroll
        for (int ks = 0; ks < 2; ++ks)
          af[q][ks] = *(const short8*)(Ab + arow0 + (2 * g + q) * 1024 + ksw[ks]);
      if (g == 0) {
#pragma unroll
        for (int nf = 0; nf < 4; ++nf)
#pragma unroll
          for (int ks = 0; ks < 2; ++ks)
            bfr[nf * 2 + ks] = *(const short8*)(Bb + brow0 + nf * 1024 + ksw[ks]);
      }

      __builtin_amdgcn_s_barrier();
      asm volatile("s_waitcnt lgkmcnt(0)" ::: "memory");
      __builtin_amdgcn_sched_barrier(0);
      __builtin_amdgcn_s_setprio(1);
#pragma unroll
      for (int ks = 0; ks < 2; ++ks)
#pragma unroll
        for (int q = 0; q < 2; ++q)
#pragma unroll
          for (int nf = 0; nf < 4; ++nf)
            acc[2 * g + q][nf] = __builtin_amdgcn_mfma_f32_16x16x32_bf16(
                af[q][ks], bfr[nf * 2 + ks], acc[2 * g + q][nf], 0, 0, 0);
      __builtin_amdgcn_s_setprio(0);

      if (ph == 3) {
        if (nl) asm volatile("s_waitcnt vmcnt(4)" ::: "memory");
        else    asm volatile("s_waitcnt vmcnt(0)" ::: "memory");
      } else if (ph == 7) {
        if (nl) asm volatile("s_waitcnt vmcnt(4)" ::: "memory");
      }
      __builtin_amdgcn_s_barrier();
    }
  }

  // ---- epilogue: route by segment; all outputs bf16; bias is spectral
  const int seg = bn >> 11;                        // 0:q 1:k 2:v
  const float* bp = biasF + (size_t)seg * 2048;
  float bias_j[4];
#pragma unroll
  for (int j = 0; j < 4; ++j)
    bias_j[j] = bp[(bn + wc * 64 + j * 16 + frow) & 2047];
  const int er = (lane >> 4) * 4;
  unsigned short* dst = (seg == 0) ? qb : kvb;
  const size_t rstride = (seg == 0) ? 2048 : 4096;
  const int coff = (seg == 2) ? 2048 : 0;
#pragma unroll
  for (int I = 0; I < 8; ++I) {
    int row = bm + wr * 128 + I * 16 + er;
#pragma unroll
    for (int j = 0; j < 4; ++j) {
      int col = (bn + wc * 64 + j * 16 + frow) & 2047;
#pragma unroll
      for (int r = 0; r < 4; ++r) {
        float val = acc[I][j][r] + bias_j[j];
        dst[(size_t)(row + r) * rstride + coff + col] = f2bf(val);
      }
    }
  }
}

// ------------------------------------------------- normalize & multiply ---
// kvb row: [Fk packed x2048 | Fv packed x2048] bf16. Writes packed
// unit(Fk)·unit(Fv) over the first 2048 ushorts.  Pure streaming.
__global__ __launch_bounds__(256)
void normmul_kernel(unsigned short* __restrict__ kvb)
{
  const size_t row = blockIdx.x;
  const int t = threadIdx.x;
  unsigned short* kvrow = kvb + row * 4096;
  ushort8 kk = *(const ushort8*)(kvrow + t * 8);
  ushort8 vv = *(const ushort8*)(kvrow + 2048 + t * 8);
  ushort8 o;
#pragma unroll
  for (int e = 0; e < 4; ++e) {
    if (t == 0 && e == 0) {
      float k0 = bf2f(kk[0]), kn = bf2f(kk[1]);
      float v0 = bf2f(vv[0]), vn = bf2f(vv[1]);
      o[0] = f2bf((k0 / (fabsf(k0) + EPS_)) * (v0 / (fabsf(v0) + EPS_)));
      o[1] = f2bf((kn / (fabsf(kn) + EPS_)) * (vn / (fabsf(vn) + EPS_)));
    } else {
      float2 Fk = mkf2(bf2f(kk[2*e]), bf2f(kk[2*e+1]));
      float2 Fv = mkf2(bf2f(vv[2*e]), bf2f(vv[2*e+1]));
      float sa = 1.f / (sqrtf(Fk.x*Fk.x + Fk.y*Fk.y) + EPS_);
      float sb = 1.f / (sqrtf(Fv.x*Fv.x + Fv.y*Fv.y) + EPS_);
      float2 p = cmulf(Fk, Fv);
      float sc = sa * sb;
      o[2*e]   = f2bf(p.x * sc);
      o[2*e+1] = f2bf(p.y * sc);
    }
  }
  *(ushort8*)(kvrow + t * 8) = o;
}

// --------------------------------------------------------------- scan -----
__global__ __launch_bounds__(256)
void scan_partial(const unsigned short* __restrict__ kvb, float2* __restrict__ part)
{
  int gid = blockIdx.x * 256 + threadIdx.x;        // 0 .. 32767
  int q4 = gid & 255;
  int chunk = (gid >> 8) & (NCHUNK - 1);
  int b = gid >> 14;
  const unsigned short* p = kvb + (size_t)(b * S_DIM + chunk * CHLEN) * 4096 + q4 * 8;
  float ar[4] = {0,0,0,0}, ai[4] = {0,0,0,0};
  for (int s = 0; s < CHLEN; ++s) {
    ushort8 v = *(const ushort8*)(p + (size_t)s * 4096);
#pragma unroll
    for (int e = 0; e < 4; ++e) { ar[e] += bf2f(v[2*e]); ai[e] += bf2f(v[2*e+1]); }
  }
  float2* pp = part + (size_t)(b * NCHUNK + chunk) * HALF_D + q4 * 4;
#pragma unroll
  for (int e = 0; e < 4; ++e) pp[e] = mkf2(ar[e], ai[e]);
}

__global__ __launch_bounds__(256)
void scan_apply(unsigned short* __restrict__ kvb, const float2* __restrict__ part)
{
  int gid = blockIdx.x * 256 + threadIdx.x;
  int q4 = gid & 255;
  int chunk = (gid >> 8) & (NCHUNK - 1);
  int b = gid >> 14;
  unsigned short* p = kvb + (size_t)(b * S_DIM + chunk * CHLEN) * 4096 + q4 * 8;
  const float2* pb = part + (size_t)b * (NCHUNK * HALF_D) + q4 * 4;
  float ar[4] = {0.f,0.f,0.f,0.f}, ai[4] = {0.f,0.f,0.f,0.f};
  for (int c = 0; c < chunk; ++c) {
    const float2* pp = pb + (size_t)c * HALF_D;
#pragma unroll
    for (int e = 0; e < 4; ++e) { float2 v = pp[e]; ar[e] += v.x; ai[e] += v.y; }
  }
  for (int s = 0; s < CHLEN; ++s) {
    ushort8 v = *(const ushort8*)(p + (size_t)s * 4096);
    ushort8 o;
#pragma unroll
    for (int e = 0; e < 4; ++e) {
      ar[e] += bf2f(v[2*e]); ai[e] += bf2f(v[2*e+1]);
      o[2*e] = f2bf(ar[e]); o[2*e+1] = f2bf(ai[e]);
    }
    *(ushort8*)(p + (size_t)s * 4096) = o;
  }
}

// --------------------------------------------------------------- final ----
// TWO rows per block; Fq read DIRECTLY from qb (spectral GEMM output).
//   G0 = conj(Fq0)·M0,  G1 = conj(Fq1)·M1;  y = ifft(G0 + i G1);
//   out0 = Re(y), out1 = Im(y).  Only ONE (inverse) FFT per 2 rows.
__global__ __launch_bounds__(256)
void final_kernel(const unsigned short* __restrict__ qb,
                  const unsigned short* __restrict__ kvb,
                  const float* __restrict__ base, const float* __restrict__ gate,
                  float* __restrict__ out)
{
  __shared__ float2 X[D_DIM];
  __shared__ float twr[HALF_D], twi[HALF_D];
  const int t = threadIdx.x;
  const size_t row0 = (size_t)blockIdx.x * 2;
  const unsigned short* q0p = qb + row0 * 2048;
  const unsigned short* q1p = q0p + 2048;
  const unsigned short* m0 = kvb + row0 * 4096;
  const unsigned short* m1 = m0 + 4096;

  load_twiddles_ls(twr, twi, t);
  for (int d = t; d < HALF_D; d += 256) {
    if (d == 0) {
      float M00 = bf2f(m0[0]), M0N = bf2f(m0[1]);
      float M10 = bf2f(m1[0]), M1N = bf2f(m1[1]);
      X[XS(0)]      = mkf2(bf2f(q0p[0]) * M00, bf2f(q1p[0]) * M10);
      X[XS(HALF_D)] = mkf2(bf2f(q0p[1]) * M0N, bf2f(q1p[1]) * M1N);
    } else {
      float2 Fq0 = mkf2(bf2f(q0p[2*d]), bf2f(q0p[2*d+1]));
      float2 Fq1 = mkf2(bf2f(q1p[2*d]), bf2f(q1p[2*d+1]));
      float2 M0d = mkf2(bf2f(m0[2*d]), bf2f(m0[2*d+1]));
      float2 M1d = mkf2(bf2f(m1[2*d]), bf2f(m1[2*d+1]));
      float2 G0 = mkf2(Fq0.x*M0d.x + Fq0.y*M0d.y, Fq0.x*M0d.y - Fq0.y*M0d.x);
      float2 G1 = mkf2(Fq1.x*M1d.x + Fq1.y*M1d.y, Fq1.x*M1d.y - Fq1.y*M1d.x);
      X[XS(d)]         = mkf2(G0.x - G1.y, G0.y + G1.x);
      X[XS(D_DIM - d)] = mkf2(G0.x + G1.y, G1.x - G0.y);
    }
  }
  __syncthreads();
  fft_inv(X, twr, twi, t);

  const float gv = gate[0] * (1.f / (float)D_DIM);
  const float* brow = base + row0 * 2048;
  float* orow = out + row0 * 2048;
  for (int i = t; i < D_DIM; i += 256) {
    int p = __brev((unsigned)i) >> 21;
    float2 y = X[XS(p)];
    orow[i]        = brow[i]        + gv * y.x;
    orow[2048 + i] = brow[2048 + i] + gv * y.y;
  }
}

// ------------------------------------------------------------ launcher ----
extern "C" void kernel_launch(void* const* d_in, const int* in_sizes, int n_in,
                              void* d_out, int out_size, void* d_ws, size_t ws_size,
                              hipStream_t stream)
{
  const float* hs   = (const float*)d_in[0];
  const float* base = (const float*)d_in[1];
  const float* Wq   = (const float*)d_in[2];
  const float* bq   = (const float*)d_in[3];
  const float* Wk   = (const float*)d_in[4];
  const float* bk   = (const float*)d_in[5];
  const float* Wv   = (const float*)d_in[6];
  const float* bv   = (const float*)d_in[7];
  const float* gate = (const float*)d_in[8];
  float* out  = (float*)d_out;

  // workspace layout (160.4 MB, same as R10):
  //   hsb   bf16 [8192][2048]                 @ 0
  //   wspec bf16 [6144][2048] spectral W      @ 33554432
  //   kvb   [8192] x 8KB rows (Fk|Fv -> Fkv/Fmem) @ 58720256
  //   qb    bf16 [8192][2048] (packed Fq)     @ 125829120
  //   part  f32x2 [2][64][1024]               @ 159383552
  //         (first 24KB of part double as biasF f32[3][2048] pre-scan)
  char* ws = (char*)d_ws;
  unsigned short* hsb   = (unsigned short*)ws;
  unsigned short* wspec = (unsigned short*)(ws + 33554432);
  unsigned short* kvb   = (unsigned short*)(ws + 58720256);
  unsigned short* qb    = (unsigned short*)(ws + 58720256 + 67108864);
  float2* part  = (float2*)(ws + 58720256 + 67108864 + 33554432);
  float*  biasF = (float*)part;    // dead before scan_partial runs

  cvt_hs<<<8192, 256, 0, stream>>>(hs, hsb);
  wfft_kernel<<<3072, 256, 0, stream>>>(Wq, Wk, Wv, wspec);
  biasfft_kernel<<<3, 256, 0, stream>>>(bq, bk, bv, biasF);

  gemm_fused<<<768, 512, 0, stream>>>(hsb, wspec, biasF, qb, kvb);

  normmul_kernel<<<NROW, 256, 0, stream>>>(kvb);

  scan_partial<<<128, 256, 0, stream>>>(kvb, part);
  scan_apply<<<128, 256, 0, stream>>>(kvb, part);

  final_kernel<<<NROW / 2, 256, 0, stream>>>(qb, kvb, base, gate, out);
}

// Round 12
// 351.503 us; speedup vs baseline: 1.0549x; 1.0549x over previous
//
#include <hip/hip_runtime.h>
#include <math.h>

constexpr int D_DIM  = 2048;   // feature dim (FFT length)
constexpr int HALF_D = 1024;
constexpr int B_DIM  = 2;
constexpr int S_DIM  = 4096;
constexpr int NROW   = B_DIM * S_DIM;      // 8192
constexpr int NCHUNK = 64;                 // scan chunks along S
constexpr int CHLEN  = S_DIM / NCHUNK;     // 64
constexpr float EPS_ = 1e-8f;

typedef __attribute__((ext_vector_type(8))) short  short8;   // bf16x8 frag
typedef __attribute__((ext_vector_type(8))) unsigned short ushort8;
typedef __attribute__((ext_vector_type(4))) float  f32x4;    // MFMA acc

__device__ __forceinline__ float2 mkf2(float x, float y){ float2 r; r.x=x; r.y=y; return r; }
__device__ __forceinline__ float2 cmulf(float2 a, float2 b){
  return mkf2(fmaf(a.x, b.x, -a.y*b.y), fmaf(a.x, b.y, a.y*b.x));
}
__device__ __forceinline__ unsigned short f2bf(float x){
  unsigned u = __float_as_uint(x);
  u += 0x7fff + ((u >> 16) & 1);           // round-to-nearest-even
  return (unsigned short)(u >> 16);
}
__device__ __forceinline__ float bf2f(unsigned short h){
  return __uint_as_float(((unsigned)h) << 16);
}

// ----------------------------------------------- fp32→bf16 (all inputs) ---
// i in [0, n8): hs -> hsb.  i in [n8, n8+3*w8): Wq|Wk|Wv -> wb (contiguous).
__global__ __launch_bounds__(256)
void cvt_inputs(const float* __restrict__ hs, const float* __restrict__ Wq,
                const float* __restrict__ Wk, const float* __restrict__ Wv,
                unsigned short* __restrict__ hsb, unsigned short* __restrict__ wb)
{
  constexpr int n8 = (NROW * D_DIM) / 8;          // 2097152
  constexpr int w8 = (D_DIM * D_DIM) / 8;         // 524288
  int i = blockIdx.x * 256 + threadIdx.x;
  const float* src;
  unsigned short* dst;
  int local;
  if (i < n8) { src = hs; local = i; dst = hsb + (size_t)i * 8; }
  else {
    int j = i - n8;
    int seg = j >> 19;                            // j / w8
    local = j & (w8 - 1);
    src = (seg == 0) ? Wq : (seg == 1) ? Wk : Wv;
    dst = wb + (size_t)j * 8;
  }
  const float4* p = (const float4*)src + (size_t)local * 2;
  float4 a = p[0], b = p[1];
  ushort8 o;
  o[0]=f2bf(a.x); o[1]=f2bf(a.y); o[2]=f2bf(a.z); o[3]=f2bf(a.w);
  o[4]=f2bf(b.x); o[5]=f2bf(b.y); o[6]=f2bf(b.z); o[7]=f2bf(b.w);
  *(ushort8*)dst = o;
}

// -------------- fused q/k/v 256x256 MFMA GEMM, 8-phase schedule (m201) ----
// A [8192][2048] bf16, Wc [6144][2048] bf16 (Wq|Wk|Wv rows concatenated).
// C = A @ Wc^T + bias; q -> bf16 qb, k/v -> bf16 interleaved kvb rows.
// 8 waves (2Mx4N), per-wave 128x64 out, BK=64, 2 K-tiles / 8 phases per
// iteration, dead-region half-tile staging, vmcnt(4) only at phases 3/7,
// 8-chunk XOR LDS swizzle (conflict-free), setprio around MFMA clusters.
__global__ __launch_bounds__(512, 2)
void gemm_fused(const unsigned short* __restrict__ A,
                const unsigned short* __restrict__ Wc,
                const float* __restrict__ bq, const float* __restrict__ bk,
                const float* __restrict__ bv,
                unsigned short* __restrict__ qb, unsigned short* __restrict__ kvb)
{
  constexpr int K = 2048, NITER = 16;             // 32 K-tiles, 2/iter
  __shared__ unsigned short lds[65536];           // 128 KB: A[2][16K] B[2][16K]
  const int tid  = threadIdx.x;
  const int wid  = tid >> 6, lane = tid & 63;
  const int wr   = wid >> 2, wc = wid & 3;

  // XCD-bijective swizzle: 768 blocks = 96 per XCD; chunk = 4 M x 24 N
  int bid = blockIdx.x;
  int sw  = (bid & 7) * 96 + (bid >> 3);
  const int bm = (sw / 24) * 256, bn = (sw % 24) * 256;

  // staging coords: one gload covers 64 rows x 64 k (8 KB); lane row tid>>3,
  // stored chunk tid&7 holds global k-chunk (tid&7)^(row&7)  (8 elem chunks)
  const int srow = tid >> 3;                       // 0..63
  const int skc  = ((tid & 7) ^ (srow & 7)) * 8;
  const unsigned short* Ag = A  + (size_t)(bm + srow) * K + skc;
  const unsigned short* Bg = Wc + (size_t)(bn + srow) * K + skc;
  unsigned short* Al = lds;
  unsigned short* Bl = lds + 32768;
  const int stoff = wid * 512;                     // wave-uniform dest

  auto stA = [&](int kt, int d, int h, int r) {
    __builtin_amdgcn_global_load_lds(
      (const __attribute__((address_space(1))) void*)(Ag + (size_t)(h * 128 + r * 64) * K + kt * 64),
      (__attribute__((address_space(3))) void*)(Al + d * 16384 + h * 8192 + r * 4096 + stoff),
      16, 0, 0);
  };
  auto stB = [&](int kt, int d, int h, int r) {
    __builtin_amdgcn_global_load_lds(
      (const __attribute__((address_space(1))) void*)(Bg + (size_t)(h * 128 + r * 64) * K + kt * 64),
      (__attribute__((address_space(3))) void*)(Bl + d * 16384 + h * 8192 + r * 4096 + stoff),
      16, 0, 0);
  };

  // fragment read coords: row stride 64 ushorts; k-chunk XOR-swizzled by row
  const int frow = lane & 15;
  const int kq   = lane >> 4;                      // 0..3
  int ksw[2];
  ksw[0] = ((0 * 4 + kq) ^ (frow & 7)) * 8;
  ksw[1] = ((1 * 4 + kq) ^ (frow & 7)) * 8;
  const int arow0 = (wr * 128 + frow) * 64;        // + mf*1024 + ksw[ks]
  const int brow0 = (wc * 64 + frow) * 64;         // + nf*1024 + ksw[ks]

  f32x4 acc[8][4];
#pragma unroll
  for (int i = 0; i < 8; ++i)
#pragma unroll
    for (int j = 0; j < 4; ++j) acc[i][j] = (f32x4){0.f, 0.f, 0.f, 0.f};

  // prologue: A(0),B(0) -> dbuf0; B(1) -> dbuf1.B  (A(1) staged at P0/P1)
  stA(0, 0, 0, 0); stA(0, 0, 0, 1); stA(0, 0, 1, 0); stA(0, 0, 1, 1);
  stB(0, 0, 0, 0); stB(0, 0, 0, 1); stB(0, 0, 1, 0); stB(0, 0, 1, 1);
  stB(1, 1, 0, 0); stB(1, 1, 0, 1); stB(1, 1, 1, 0); stB(1, 1, 1, 1);
  asm volatile("s_waitcnt vmcnt(4)" ::: "memory");
  __builtin_amdgcn_s_barrier();
  __builtin_amdgcn_sched_barrier(0);

#pragma unroll 1
  for (int it = 0; it < NITER; ++it) {
    const bool nl = (it < NITER - 1);
    const int t1 = 2 * it + 1;
    short8 bfr[8];
#pragma unroll
    for (int ph = 0; ph < 8; ++ph) {
      const int g  = ph & 3;
      const int db = ph >> 2;                      // dbuf being computed
      const unsigned short* Ab = Al + db * 16384;
      const unsigned short* Bb = Bl + db * 16384;

      // --- stage one half-tile (dead-region schedule) ---
      if      (ph == 0) { stA(t1, 1, 0, 0); stA(t1, 1, 0, 1); }
      else if (ph == 1) { stA(t1, 1, 1, 0); stA(t1, 1, 1, 1); }
      else if (ph == 2) { if (nl) { stB(t1 + 1, 0, 0, 0); stB(t1 + 1, 0, 0, 1); } }
      else if (ph == 3) { if (nl) { stB(t1 + 1, 0, 1, 0); stB(t1 + 1, 0, 1, 1); } }
      else if (ph == 4) { if (nl) { stA(t1 + 1, 0, 0, 0); stA(t1 + 1, 0, 0, 1); } }
      else if (ph == 5) { if (nl) { stA(t1 + 1, 0, 1, 0); stA(t1 + 1, 0, 1, 1); } }
      else if (ph == 6) { if (nl) { stB(t1 + 2, 1, 0, 0); stB(t1 + 2, 1, 0, 1); } }
      else              { if (nl) { stB(t1 + 2, 1, 1, 0); stB(t1 + 2, 1, 1, 1); } }

      // --- ds reads: A quadrant every phase; B once per K-tile ---
      short8 af[2][2];
#pragma unroll
      for (int q = 0; q < 2; ++q)
#pragma unroll
        for (int ks = 0; ks < 2; ++ks)
          af[q][ks] = *(const short8*)(Ab + arow0 + (2 * g + q) * 1024 + ksw[ks]);
      if (g == 0) {
#pragma unroll
        for (int nf = 0; nf < 4; ++nf)
#pragma unroll
          for (int ks = 0; ks < 2; ++ks)
            bfr[nf * 2 + ks] = *(const short8*)(Bb + brow0 + nf * 1024 + ksw[ks]);
      }

      __builtin_amdgcn_s_barrier();
      asm volatile("s_waitcnt lgkmcnt(0)" ::: "memory");
      __builtin_amdgcn_sched_barrier(0);
      __builtin_amdgcn_s_setprio(1);
#pragma unroll
      for (int ks = 0; ks < 2; ++ks)
#pragma unroll
        for (int q = 0; q < 2; ++q)
#pragma unroll
          for (int nf = 0; nf < 4; ++nf)
            acc[2 * g + q][nf] = __builtin_amdgcn_mfma_f32_16x16x32_bf16(
                af[q][ks], bfr[nf * 2 + ks], acc[2 * g + q][nf], 0, 0, 0);
      __builtin_amdgcn_s_setprio(0);

      if (ph == 3) {
        if (nl) asm volatile("s_waitcnt vmcnt(4)" ::: "memory");
        else    asm volatile("s_waitcnt vmcnt(0)" ::: "memory");
      } else if (ph == 7) {
        if (nl) asm volatile("s_waitcnt vmcnt(4)" ::: "memory");
      }
      __builtin_amdgcn_s_barrier();
    }
  }

  // ---- epilogue: route by segment; all outputs bf16
  const int seg = bn >> 11;                        // 0:q 1:k 2:v
  const float* bp = (seg == 0) ? bq : (seg == 1) ? bk : bv;
  float bias_j[4];
#pragma unroll
  for (int j = 0; j < 4; ++j)
    bias_j[j] = bp[(bn + wc * 64 + j * 16 + frow) & 2047];
  const int er = (lane >> 4) * 4;
  unsigned short* dst = (seg == 0) ? qb : kvb;
  const size_t rstride = (seg == 0) ? 2048 : 4096;
  const int coff = (seg == 2) ? 2048 : 0;
#pragma unroll
  for (int I = 0; I < 8; ++I) {
    int row = bm + wr * 128 + I * 16 + er;
#pragma unroll
    for (int j = 0; j < 4; ++j) {
      int col = (bn + wc * 64 + j * 16 + frow) & 2047;
#pragma unroll
      for (int r = 0; r < 4; ++r) {
        float val = acc[I][j][r] + bias_j[j];
        dst[(size_t)(row + r) * rstride + coff + col] = f2bf(val);
      }
    }
  }
}

// ------------------------------------------------------------- FFT core ---
// 2048-pt FFT, 256 threads, radix 8-8-8-4 macro-stages, register butterflies.
__device__ __forceinline__ int XS(int i){ return i ^ (((i >> 5) ^ (i >> 10)) & 31); }
__device__ __forceinline__ int TS(int i){ return i ^ ((i >> 5) & 31); }

__device__ __forceinline__ float2 mulmi(float2 w){ return mkf2(w.y, -w.x); }   // w * (-i)
__device__ __forceinline__ float2 mulw8(float2 w){                              // w * e^{-i pi/4}
  const float c = 0.70710678118654752f;
  return mkf2(c * (w.x + w.y), c * (w.y - w.x));
}
__device__ __forceinline__ void bfly(float2& a, float2& b, float2 w){
  float2 v = cmulf(w, b);
  b = mkf2(a.x - v.x, a.y - v.y);
  a = mkf2(a.x + v.x, a.y + v.y);
}
__device__ __forceinline__ void bflyc(float2& a, float2& b, float2 w){
  float2 d = mkf2(a.x - b.x, a.y - b.y);
  a = mkf2(a.x + b.x, a.y + b.y);
  b = mkf2(fmaf(d.x, w.x, d.y * w.y), fmaf(d.y, w.x, -d.x * w.y));  // d * conj(w)
}

__device__ __forceinline__ void fwd8(float2 e[8], float2 wA, float2 wB0, float2 wC0){
  bfly(e[0], e[1], wA); bfly(e[2], e[3], wA); bfly(e[4], e[5], wA); bfly(e[6], e[7], wA);
  float2 wB1 = mulmi(wB0);
  bfly(e[0], e[2], wB0); bfly(e[1], e[3], wB1); bfly(e[4], e[6], wB0); bfly(e[5], e[7], wB1);
  float2 wC1 = mulw8(wC0), wC2 = mulmi(wC0), wC3 = mulmi(wC1);
  bfly(e[0], e[4], wC0); bfly(e[1], e[5], wC1); bfly(e[2], e[6], wC2); bfly(e[3], e[7], wC3);
}
__device__ __forceinline__ void inv8(float2 e[8], float2 wA, float2 wB0, float2 wC0){
  float2 wC1 = mulw8(wC0), wC2 = mulmi(wC0), wC3 = mulmi(wC1);
  bflyc(e[0], e[4], wC0); bflyc(e[1], e[5], wC1); bflyc(e[2], e[6], wC2); bflyc(e[3], e[7], wC3);
  float2 wB1 = mulmi(wB0);
  bflyc(e[0], e[2], wB0); bflyc(e[1], e[3], wB1); bflyc(e[4], e[6], wB0); bflyc(e[5], e[7], wB1);
  bflyc(e[0], e[1], wA); bflyc(e[2], e[3], wA); bflyc(e[4], e[5], wA); bflyc(e[6], e[7], wA);
}

__device__ __forceinline__ float2 twld(const float* twr, const float* twi, int i){
  int s = TS(i);
  return mkf2(twr[s], twi[s]);
}

__device__ void fft_fwd(float2* X, const float* twr, const float* twi, int t)
{
  const float2 one = mkf2(1.f, 0.f);
  {                                   // MS1
    int b = 8 * t;
    float2 e[8];
#pragma unroll
    for (int r = 0; r < 8; ++r) e[r] = X[XS(b + r)];
    fwd8(e, one, one, one);
#pragma unroll
    for (int r = 0; r < 8; ++r) X[XS(b + r)] = e[r];
  }
  __syncthreads();
  {                                   // MS2
    int u = t >> 5, b = 64 * (t & 31) + u;
    float2 e[8];
#pragma unroll
    for (int r = 0; r < 8; ++r) e[r] = X[XS(b + 8 * r)];
    fwd8(e, twld(twr,twi,128*u), twld(twr,twi,64*u), twld(twr,twi,32*u));
#pragma unroll
    for (int r = 0; r < 8; ++r) X[XS(b + 8 * r)] = e[r];
  }
  __syncthreads();
  {                                   // MS3
    int u = t & 63, b = 512 * (t >> 6) + u;
    float2 e[8];
#pragma unroll
    for (int r = 0; r < 8; ++r) e[r] = X[XS(b + 64 * r)];
    fwd8(e, twld(twr,twi,16*u), twld(twr,twi,8*u), twld(twr,twi,4*u));
#pragma unroll
    for (int r = 0; r < 8; ++r) X[XS(b + 64 * r)] = e[r];
  }
  __syncthreads();
#pragma unroll
  for (int h = 0; h < 2; ++h) {       // MS4: radix-4
    int u = t + 256 * h;
    float2 f[4];
#pragma unroll
    for (int r = 0; r < 4; ++r) f[r] = X[XS(u + 512 * r)];
    float2 wA = twld(twr,twi,2*u), wB0 = twld(twr,twi,u), wB1 = mulmi(wB0);
    bfly(f[0], f[1], wA);  bfly(f[2], f[3], wA);
    bfly(f[0], f[2], wB0); bfly(f[1], f[3], wB1);
#pragma unroll
    for (int r = 0; r < 4; ++r) X[XS(u + 512 * r)] = f[r];
  }
  __syncthreads();
}

__device__ void fft_inv(float2* X, const float* twr, const float* twi, int t)
{
  const float2 one = mkf2(1.f, 0.f);
#pragma unroll
  for (int h = 0; h < 2; ++h) {       // MS4'
    int u = t + 256 * h;
    float2 f[4];
#pragma unroll
    for (int r = 0; r < 4; ++r) f[r] = X[XS(u + 512 * r)];
    float2 wA = twld(twr,twi,2*u), wB0 = twld(twr,twi,u), wB1 = mulmi(wB0);
    bflyc(f[0], f[2], wB0); bflyc(f[1], f[3], wB1);
    bflyc(f[0], f[1], wA);  bflyc(f[2], f[3], wA);
#pragma unroll
    for (int r = 0; r < 4; ++r) X[XS(u + 512 * r)] = f[r];
  }
  __syncthreads();
  {                                   // MS3'
    int u = t & 63, b = 512 * (t >> 6) + u;
    float2 e[8];
#pragma unroll
    for (int r = 0; r < 8; ++r) e[r] = X[XS(b + 64 * r)];
    inv8(e, twld(twr,twi,16*u), twld(twr,twi,8*u), twld(twr,twi,4*u));
#pragma unroll
    for (int r = 0; r < 8; ++r) X[XS(b + 64 * r)] = e[r];
  }
  __syncthreads();
  {                                   // MS2'
    int u = t >> 5, b = 64 * (t & 31) + u;
    float2 e[8];
#pragma unroll
    for (int r = 0; r < 8; ++r) e[r] = X[XS(b + 8 * r)];
    inv8(e, twld(twr,twi,128*u), twld(twr,twi,64*u), twld(twr,twi,32*u));
#pragma unroll
    for (int r = 0; r < 8; ++r) X[XS(b + 8 * r)] = e[r];
  }
  __syncthreads();
  {                                   // MS1'
    int b = 8 * t;
    float2 e[8];
#pragma unroll
    for (int r = 0; r < 8; ++r) e[r] = X[XS(b + r)];
    inv8(e, one, one, one);
#pragma unroll
    for (int r = 0; r < 8; ++r) X[XS(b + r)] = e[r];
  }
  __syncthreads();
}

// ------------------------------------------------------- twiddle table ----
__global__ __launch_bounds__(256)
void twiddle_init(float2* __restrict__ twg)
{
  int i = blockIdx.x * 256 + threadIdx.x;
  if (i < HALF_D) {
    float sv, cv;
    sincosf(-6.283185307179586f * (float)i / (float)D_DIM, &sv, &cv);
    twg[i] = mkf2(cv, sv);
  }
}

// ---------------------------------------------------------- FFT(k,v)·mul --
// kvb row r: [k bf16 x2048 | v bf16 x2048]. One complex FFT of (k + i·v)
// recovers both spectra; writes packed half-spectrum of unit(Fk)·unit(Fv)
// as bf16 pairs (re,im) into the first 2048 ushorts of the row slot.
__global__ __launch_bounds__(256)
void fftkv_kernel(unsigned short* __restrict__ kvb, const float2* __restrict__ twg)
{
  __shared__ float2 X[D_DIM];
  __shared__ float twr[HALF_D], twi[HALF_D];
  const int t = threadIdx.x;
  const size_t row = blockIdx.x;
  const unsigned short* kvrow = kvb + row * 4096;

  for (int i = t; i < HALF_D; i += 256) {
    float2 w = twg[i]; int s = TS(i); twr[s] = w.x; twi[s] = w.y;
  }
  {
    int i0 = t * 8;
    ushort8 k8 = *(const ushort8*)(kvrow + i0);
    ushort8 v8 = *(const ushort8*)(kvrow + 2048 + i0);
#pragma unroll
    for (int r = 0; r < 8; ++r) {
      int i = i0 + r;
      int p = __brev((unsigned)i) >> 21;
      X[XS(p)] = mkf2(bf2f(k8[r]), bf2f(v8[r]));
    }
  }
  __syncthreads();
  fft_fwd(X, twr, twi, t);

  unsigned int* outp = (unsigned int*)(kvb + row * 4096);
  for (int d = t; d < HALF_D; d += 256) {
    float2 p;
    if (d == 0) {
      float2 z0 = X[XS(0)], zn = X[XS(HALF_D)];
      float k0 = z0.x, v0 = z0.y, kn = zn.x, vn = zn.y;
      float p0 = (k0 / (fabsf(k0) + EPS_)) * (v0 / (fabsf(v0) + EPS_));
      float pn = (kn / (fabsf(kn) + EPS_)) * (vn / (fabsf(vn) + EPS_));
      p = mkf2(p0, pn);
    } else {
      float2 A = X[XS(d)];
      float2 Bc = X[XS(D_DIM - d)];
      float2 Bj = mkf2(Bc.x, -Bc.y);
      float2 Fk = mkf2(0.5f * (A.x + Bj.x), 0.5f * (A.y + Bj.y));
      float2 tt = mkf2(0.5f * (A.x - Bj.x), 0.5f * (A.y - Bj.y));
      float2 Fv = mkf2(tt.y, -tt.x);
      float sa = 1.f / (sqrtf(Fk.x*Fk.x + Fk.y*Fk.y) + EPS_);
      float sb = 1.f / (sqrtf(Fv.x*Fv.x + Fv.y*Fv.y) + EPS_);
      p = cmulf(Fk, Fv);
      float sc = sa * sb;
      p.x *= sc; p.y *= sc;
    }
    outp[d] = (unsigned)f2bf(p.x) | ((unsigned)f2bf(p.y) << 16);
  }
}

// --------------------------------------------------------------- scan -----
// Spectra stored as bf16 pairs, 4 bins (16B) per thread; f32 accumulators
// and f32 chunk partials. part layout [b][chunk][1024] float2.
__global__ __launch_bounds__(256)
void scan_partial(const unsigned short* __restrict__ kvb, float2* __restrict__ part)
{
  int gid = blockIdx.x * 256 + threadIdx.x;        // 0 .. 32767
  int q4 = gid & 255;
  int chunk = (gid >> 8) & (NCHUNK - 1);
  int b = gid >> 14;
  const unsigned short* p = kvb + (size_t)(b * S_DIM + chunk * CHLEN) * 4096 + q4 * 8;
  float ar[4] = {0,0,0,0}, ai[4] = {0,0,0,0};
  for (int s = 0; s < CHLEN; ++s) {
    ushort8 v = *(const ushort8*)(p + (size_t)s * 4096);
#pragma unroll
    for (int e = 0; e < 4; ++e) { ar[e] += bf2f(v[2*e]); ai[e] += bf2f(v[2*e+1]); }
  }
  float2* pp = part + (size_t)(b * NCHUNK + chunk) * HALF_D + q4 * 4;
#pragma unroll
  for (int e = 0; e < 4; ++e) pp[e] = mkf2(ar[e], ai[e]);
}

__global__ __launch_bounds__(256)
void scan_offsets(float2* __restrict__ part)
{
  int gid = blockIdx.x * 256 + threadIdx.x;        // 0 .. B*HALF_D-1
  int d = gid & (HALF_D - 1);
  int b = gid >> 10;
  float2* p = part + (size_t)b * (NCHUNK * HALF_D) + d;
  float2 acc = mkf2(0.f, 0.f);
  for (int c = 0; c < NCHUNK; ++c) {
    float2 v = p[(size_t)c * HALF_D];
    p[(size_t)c * HALF_D] = acc;                   // exclusive prefix
    acc.x += v.x; acc.y += v.y;
  }
}

__global__ __launch_bounds__(256)
void scan_apply(unsigned short* __restrict__ kvb, const float2* __restrict__ part)
{
  int gid = blockIdx.x * 256 + threadIdx.x;
  int q4 = gid & 255;
  int chunk = (gid >> 8) & (NCHUNK - 1);
  int b = gid >> 14;
  unsigned short* p = kvb + (size_t)(b * S_DIM + chunk * CHLEN) * 4096 + q4 * 8;
  const float2* pp = part + (size_t)(b * NCHUNK + chunk) * HALF_D + q4 * 4;
  float ar[4], ai[4];
#pragma unroll
  for (int e = 0; e < 4; ++e) { float2 v = pp[e]; ar[e] = v.x; ai[e] = v.y; }
  for (int s = 0; s < CHLEN; ++s) {
    ushort8 v = *(const ushort8*)(p + (size_t)s * 4096);
    ushort8 o;
#pragma unroll
    for (int e = 0; e < 4; ++e) {
      ar[e] += bf2f(v[2*e]); ai[e] += bf2f(v[2*e+1]);
      o[2*e] = f2bf(ar[e]); o[2*e+1] = f2bf(ai[e]);
    }
    *(ushort8*)(p + (size_t)s * 4096) = o;
  }
}

// --------------------------------------------------------------- final ----
// TWO rows per block via real-FFT packing:
//   Z = FFT(q0 + i q1);  Fq0 = (Z+conj(Zrev))/2,  Fq1 = -i(Z-conj(Zrev))/2
//   G0 = conj(Fq0)·M0,  G1 = conj(Fq1)·M1   (Gk conj-symmetric, yk real)
//   y = ifft(G0 + i G1);  out0 = Re(y), out1 = Im(y).
__global__ __launch_bounds__(256)
void final_kernel(const unsigned short* __restrict__ qb,
                  const unsigned short* __restrict__ kvb,
                  const float* __restrict__ base, const float* __restrict__ gate,
                  const float2* __restrict__ twg, float* __restrict__ out)
{
  __shared__ float2 X[D_DIM];
  __shared__ float twr[HALF_D], twi[HALF_D];
  const int t = threadIdx.x;
  const size_t row0 = (size_t)blockIdx.x * 2;
  const unsigned short* qrow = qb + row0 * 2048;   // rows row0, row0+1
  const unsigned short* m0 = kvb + row0 * 4096;    // bf16 (re,im) pairs
  const unsigned short* m1 = m0 + 4096;

  for (int i = t; i < HALF_D; i += 256) {
    float2 w = twg[i]; int s = TS(i); twr[s] = w.x; twi[s] = w.y;
  }
  {
    int i0 = t * 8;
    ushort8 q0 = *(const ushort8*)(qrow + i0);
    ushort8 q1 = *(const ushort8*)(qrow + 2048 + i0);
#pragma unroll
    for (int r = 0; r < 8; ++r) {
      int i = i0 + r;
      int p = __brev((unsigned)i) >> 21;
      X[XS(p)] = mkf2(bf2f(q0[r]), bf2f(q1[r]));
    }
  }
  __syncthreads();
  fft_fwd(X, twr, twi, t);

  for (int d = t; d < HALF_D; d += 256) {
    if (d == 0) {
      float2 z0 = X[XS(0)], zn = X[XS(HALF_D)];
      float M00 = bf2f(m0[0]), M0N = bf2f(m0[1]);
      float M10 = bf2f(m1[0]), M1N = bf2f(m1[1]);
      X[XS(0)]      = mkf2(z0.x * M00, z0.y * M10);
      X[XS(HALF_D)] = mkf2(zn.x * M0N, zn.y * M1N);
    } else {
      float2 Zd = X[XS(d)];
      float2 Zn = X[XS(D_DIM - d)];
      float2 Fq0 = mkf2(0.5f * (Zd.x + Zn.x), 0.5f * (Zd.y - Zn.y));
      float2 td  = mkf2(0.5f * (Zd.x - Zn.x), 0.5f * (Zd.y + Zn.y));
      float2 Fq1 = mkf2(td.y, -td.x);              // -i * td
      float2 M0d = mkf2(bf2f(m0[2*d]), bf2f(m0[2*d+1]));
      float2 M1d = mkf2(bf2f(m1[2*d]), bf2f(m1[2*d+1]));
      float2 G0 = mkf2(Fq0.x*M0d.x + Fq0.y*M0d.y, Fq0.x*M0d.y - Fq0.y*M0d.x);
      float2 G1 = mkf2(Fq1.x*M1d.x + Fq1.y*M1d.y, Fq1.x*M1d.y - Fq1.y*M1d.x);
      X[XS(d)]         = mkf2(G0.x - G1.y, G0.y + G1.x);
      X[XS(D_DIM - d)] = mkf2(G0.x + G1.y, G1.x - G0.y);
    }
  }
  __syncthreads();
  fft_inv(X, twr, twi, t);

  const float gv = gate[0] * (1.f / (float)D_DIM);
  const float* brow = base + row0 * 2048;
  float* orow = out + row0 * 2048;
  for (int i = t; i < D_DIM; i += 256) {
    int p = __brev((unsigned)i) >> 21;
    float2 y = X[XS(p)];
    orow[i]        = brow[i]        + gv * y.x;
    orow[2048 + i] = brow[2048 + i] + gv * y.y;
  }
}

// ------------------------------------------------------------ launcher ----
extern "C" void kernel_launch(void* const* d_in, const int* in_sizes, int n_in,
                              void* d_out, int out_size, void* d_ws, size_t ws_size,
                              hipStream_t stream)
{
  const float* hs   = (const float*)d_in[0];
  const float* base = (const float*)d_in[1];
  const float* Wq   = (const float*)d_in[2];
  const float* bq   = (const float*)d_in[3];
  const float* Wk   = (const float*)d_in[4];
  const float* bk   = (const float*)d_in[5];
  const float* Wv   = (const float*)d_in[6];
  const float* bv   = (const float*)d_in[7];
  const float* gate = (const float*)d_in[8];
  float* out  = (float*)d_out;

  // workspace layout:
  //   hsb  bf16 [8192][2048]   (first 8KB reused as twiddle table post-GEMM)
  //   wqb|wkb|wvb bf16 [6144][2048] contiguous (fused weight)
  //   kvb  [8192] x 8KB rows: [k bf16 | v bf16] -> bf16 packed Fkv/Fmem
  //   qb   bf16 [8192][2048]
  //   part f32x2 [2][64][1024]
  char* ws = (char*)d_ws;
  unsigned short* hsb = (unsigned short*)ws;
  unsigned short* wqb = (unsigned short*)(ws + 33554432);
  unsigned short* kvb = (unsigned short*)(ws + 58720256);
  unsigned short* qb  = (unsigned short*)(ws + 58720256 + 67108864);
  float2* part = (float2*)(ws + 58720256 + 67108864 + 33554432);
  float2* twg  = (float2*)ws;   // overwrites hsb AFTER the GEMM consumed it

  {
    constexpr int n8 = (NROW * D_DIM) / 8;        // 2097152
    constexpr int w8 = (D_DIM * D_DIM) / 8;       // 524288
    cvt_inputs<<<(n8 + 3 * w8) / 256, 256, 0, stream>>>(hs, Wq, Wk, Wv, hsb, wqb);
  }

  gemm_fused<<<768, 512, 0, stream>>>(hsb, wqb, bq, bk, bv, qb, kvb);

  twiddle_init<<<4, 256, 0, stream>>>(twg);

  fftkv_kernel<<<NROW, 256, 0, stream>>>(kvb, twg);

  scan_partial<<<128, 256, 0, stream>>>(kvb, part);
  scan_offsets<<<(B_DIM * HALF_D) / 256, 256, 0, stream>>>(part);
  scan_apply<<<128, 256, 0, stream>>>(kvb, part);

  final_kernel<<<NROW / 2, 256, 0, stream>>>(qb, kvb, base, gate, twg, out);
}